// Round 5
// baseline (592.763 us; speedup 1.0000x reference)
//
#include <hip/hip_runtime.h>

// SectorGCN R5: bucket counting-sort (782 x 128 nodes) with LDS-staged
// coalesced scatter + LANE-PER-EDGE per-bucket gather (16 LDS atomics/edge).
// h is pre-scaled by dinv (h~ = dinv * x@W1) so the gather loop has a single
// random stream (the 64B h~ row). No per-edge global atomics.
// N=100000, E=3200000, d_in=128, d_h=16.

#define DH 16
#define BSH 7
#define BNODES 128
#define NB_MAX 784
#define CHUNK 4096

__global__ __launch_bounds__(256) void k_Ahist(const int* __restrict__ col,
                                               int* __restrict__ gCnt, int E, int NB) {
    __shared__ int lh[NB_MAX];
    const int tid = threadIdx.x;
    for (int i = tid; i < NB; i += 256) lh[i] = 0;
    __syncthreads();
    const int base = blockIdx.x * CHUNK;
    #pragma unroll
    for (int k = 0; k < 16; ++k) {
        int e = base + tid + 256 * k;
        if (e < E) atomicAdd(&lh[col[e] >> BSH], 1);
    }
    __syncthreads();
    for (int i = tid; i < NB; i += 256) {
        int v = lh[i];
        if (v) atomicAdd(&gCnt[i], v);
    }
}

__global__ __launch_bounds__(1024) void k_Ascan(const int* __restrict__ gCnt,
                                                int* __restrict__ gBase,
                                                int* __restrict__ gCursor,
                                                int NB, int E) {
    __shared__ int s[1024];
    const int t = threadIdx.x;
    int v = (t < NB) ? gCnt[t] : 0;
    s[t] = v;
    __syncthreads();
    for (int off = 1; off < 1024; off <<= 1) {
        int u = (t >= off) ? s[t - off] : 0;
        __syncthreads();
        s[t] += u;
        __syncthreads();
    }
    if (t < NB) {
        int ex = s[t] - v;
        gBase[t] = ex;
        gCursor[t] = ex;
    }
    if (t == 0) gBase[NB] = E;
}

// LDS-staged scatter: count -> local scan -> per-(block,bucket) global run
// reservation -> place sorted in LDS -> linear write-out (coalesced runs).
__global__ __launch_bounds__(256) void k_Ascatter(const int* __restrict__ row,
                                                  const int* __restrict__ col,
                                                  const float* __restrict__ ew,
                                                  int* __restrict__ gCursor,
                                                  uint2* __restrict__ edata,
                                                  int E, int NB) {
    __shared__ int lh[NB_MAX];      // counts, then delta (globalRun - localBase)
    __shared__ int lbase[NB_MAX];   // local sorted base
    __shared__ int lcur[NB_MAX];    // placement cursor
    __shared__ int tsum[256];
    __shared__ unsigned short sbuck[CHUNK];
    __shared__ uint2 stage[CHUNK];  // 32 KB
    const int tid = threadIdx.x;
    for (int i = tid; i < NB; i += 256) lh[i] = 0;
    __syncthreads();
    const int base = blockIdx.x * CHUNK;
    int r_[16], c_[16];
    float w_[16];
    #pragma unroll
    for (int k = 0; k < 16; ++k) {
        int e = base + tid + 256 * k;
        bool ok = e < E;
        c_[k] = ok ? col[e] : -1;
        r_[k] = ok ? row[e] : 0;
        w_[k] = ok ? ew[e] : 0.f;
        if (ok) atomicAdd(&lh[c_[k] >> BSH], 1);
    }
    __syncthreads();
    // local exclusive scan of lh[0..NB) : each thread sums 4, Hillis-Steele on totals
    const int t0 = tid * 4;
    int c0 = (t0 + 0 < NB) ? lh[t0 + 0] : 0;
    int c1 = (t0 + 1 < NB) ? lh[t0 + 1] : 0;
    int c2 = (t0 + 2 < NB) ? lh[t0 + 2] : 0;
    int c3 = (t0 + 3 < NB) ? lh[t0 + 3] : 0;
    int mysum = c0 + c1 + c2 + c3;
    tsum[tid] = mysum;
    __syncthreads();
    for (int off = 1; off < 256; off <<= 1) {
        int u = (tid >= off) ? tsum[tid - off] : 0;
        __syncthreads();
        tsum[tid] += u;
        __syncthreads();
    }
    int p = tsum[tid] - mysum;   // exclusive prefix for this thread's 4 buckets
    if (t0 + 0 < NB) { lbase[t0 + 0] = p; lcur[t0 + 0] = p; } p += c0;
    if (t0 + 1 < NB) { lbase[t0 + 1] = p; lcur[t0 + 1] = p; } p += c1;
    if (t0 + 2 < NB) { lbase[t0 + 2] = p; lcur[t0 + 2] = p; } p += c2;
    if (t0 + 3 < NB) { lbase[t0 + 3] = p; lcur[t0 + 3] = p; } p += c3;
    __syncthreads();
    // reserve global runs; lh[b] := globalRun - localBase
    for (int b = tid; b < NB; b += 256) {
        int cnt = lcur[b];  // placeholder read to keep order; count is in ...
    }
    // (counts were destroyed above? no: lh still holds counts) reserve:
    for (int b = tid; b < NB; b += 256) {
        int cnt = lh[b];
        if (cnt) {
            int g = atomicAdd(&gCursor[b], cnt);
            lh[b] = g - lbase[b];   // delta
        }
    }
    __syncthreads();
    // place sorted into LDS
    #pragma unroll
    for (int k = 0; k < 16; ++k) {
        if (c_[k] >= 0) {
            int b = c_[k] >> BSH;
            unsigned rem = (unsigned)(c_[k] & (BNODES - 1));
            int sp = atomicAdd(&lcur[b], 1);
            stage[sp] = make_uint2((unsigned)r_[k] | (rem << 20), __float_as_uint(w_[k]));
            sbuck[sp] = (unsigned short)b;
        }
    }
    __syncthreads();
    // linear write-out: target = delta[bucket] + slot  (coalesced within runs)
    int nE = E - base;
    if (nE > CHUNK) nE = CHUNK;
    for (int j = tid; j < nE; j += 256)
        edata[lh[sbuck[j]] + j] = stage[j];
}

// per-bucket: deg sum in LDS, dinv = rsqrt(deg + 1)
__global__ __launch_bounds__(256) void k_deg(const int* __restrict__ gBase,
                                             const uint2* __restrict__ edata,
                                             float* __restrict__ dinv, int N) {
    __shared__ float dg[BNODES];
    const int tid = threadIdx.x;
    if (tid < BNODES) dg[tid] = 0.f;
    __syncthreads();
    const int s = gBase[blockIdx.x], e = gBase[blockIdx.x + 1];
    for (int i = s + tid; i < e; i += 256) {
        uint2 ed = edata[i];
        atomicAdd(&dg[ed.x >> 20], __uint_as_float(ed.y));
    }
    __syncthreads();
    int node = (blockIdx.x << BSH) + tid;
    if (tid < BNODES && node < N) dinv[node] = rsqrtf(dg[tid] + 1.0f);
}

// h~ = dinv * (x @ W1). block = 256 = 16 nodes x 16 feats.
__global__ __launch_bounds__(256) void k_h1(const float* __restrict__ x,
                                            const float* __restrict__ W1,
                                            const float* __restrict__ dinv,
                                            float* __restrict__ hd) {
    __shared__ float Ws[128 * DH];
    __shared__ float xs[16 * 132];
    const int t = threadIdx.x;
    const int node0 = blockIdx.x * 16;
    #pragma unroll
    for (int i = 0; i < 8; ++i) Ws[t + 256 * i] = W1[t + 256 * i];
    const float4* xg = (const float4*)(x + (size_t)node0 * 128);
    #pragma unroll
    for (int it = 0; it < 2; ++it) {
        int idx = t + 256 * it;
        int n = idx >> 5, k4 = idx & 31;
        float4 v = xg[n * 32 + k4];
        *(float4*)(&xs[n * 132 + k4 * 4]) = v;
    }
    __syncthreads();
    const int node = t >> 4, feat = t & 15;
    const float* xr = &xs[node * 132];
    float acc = 0.f;
    #pragma unroll 8
    for (int k = 0; k < 128; ++k) acc += xr[k] * Ws[k * DH + feat];
    const int v = node0 + node;
    hd[(size_t)v * DH + feat] = dinv[v] * acc;
}

// lane-per-edge layer-1 gather + fused finalize.
// acc[rem][f] += w * h~[r][f]; then q = dinv * sum_f relu(dinv*(acc+h~self)+b1)*W2
__global__ __launch_bounds__(256) void k_gather1(
    const int* __restrict__ gBase, const uint2* __restrict__ edata,
    const float* __restrict__ hd, const float* __restrict__ dinv,
    const float* __restrict__ b1, const float* __restrict__ W2,
    float* __restrict__ q, int N) {
    __shared__ float acc[BNODES][DH + 1];
    __shared__ float b1s[DH], W2s[DH];
    const int tid = threadIdx.x;
    if (tid < DH) { b1s[tid] = b1[tid]; W2s[tid] = W2[tid]; }
    for (int i = tid; i < BNODES * (DH + 1); i += 256) ((float*)acc)[i] = 0.f;
    __syncthreads();
    const int b = blockIdx.x;
    const int s = gBase[b], e = gBase[b + 1];
    for (int i = s + tid; i < e; i += 512) {
        uint2 ed0 = edata[i];
        int i1 = i + 256;
        uint2 ed1 = (i1 < e) ? edata[i1] : make_uint2(0u, 0u);  // dummy: w=0 -> +0 to acc[0]
        int r0 = ed0.x & 0xFFFFF, rem0 = ed0.x >> 20;
        int r1 = ed1.x & 0xFFFFF, rem1 = ed1.x >> 20;
        float w0 = __uint_as_float(ed0.y), w1 = __uint_as_float(ed1.y);
        const float4* h0 = (const float4*)(hd + (size_t)r0 * DH);
        const float4* h1 = (const float4*)(hd + (size_t)r1 * DH);
        float4 A0 = h0[0], B0 = h0[1], C0 = h0[2], D0 = h0[3];
        float4 A1 = h1[0], B1 = h1[1], C1 = h1[2], D1 = h1[3];
        float* a0 = acc[rem0];
        atomicAdd(a0 + 0,  w0 * A0.x); atomicAdd(a0 + 1,  w0 * A0.y);
        atomicAdd(a0 + 2,  w0 * A0.z); atomicAdd(a0 + 3,  w0 * A0.w);
        atomicAdd(a0 + 4,  w0 * B0.x); atomicAdd(a0 + 5,  w0 * B0.y);
        atomicAdd(a0 + 6,  w0 * B0.z); atomicAdd(a0 + 7,  w0 * B0.w);
        atomicAdd(a0 + 8,  w0 * C0.x); atomicAdd(a0 + 9,  w0 * C0.y);
        atomicAdd(a0 + 10, w0 * C0.z); atomicAdd(a0 + 11, w0 * C0.w);
        atomicAdd(a0 + 12, w0 * D0.x); atomicAdd(a0 + 13, w0 * D0.y);
        atomicAdd(a0 + 14, w0 * D0.z); atomicAdd(a0 + 15, w0 * D0.w);
        float* a1 = acc[rem1];
        atomicAdd(a1 + 0,  w1 * A1.x); atomicAdd(a1 + 1,  w1 * A1.y);
        atomicAdd(a1 + 2,  w1 * A1.z); atomicAdd(a1 + 3,  w1 * A1.w);
        atomicAdd(a1 + 4,  w1 * B1.x); atomicAdd(a1 + 5,  w1 * B1.y);
        atomicAdd(a1 + 6,  w1 * B1.z); atomicAdd(a1 + 7,  w1 * B1.w);
        atomicAdd(a1 + 8,  w1 * C1.x); atomicAdd(a1 + 9,  w1 * C1.y);
        atomicAdd(a1 + 10, w1 * C1.z); atomicAdd(a1 + 11, w1 * C1.w);
        atomicAdd(a1 + 12, w1 * D1.x); atomicAdd(a1 + 13, w1 * D1.y);
        atomicAdd(a1 + 14, w1 * D1.z); atomicAdd(a1 + 15, w1 * D1.w);
    }
    __syncthreads();
    int node = (b << BSH) + tid;
    if (tid < BNODES && node < N) {
        float dc = dinv[node];
        const float4* hs = (const float4*)(hd + (size_t)node * DH);
        float t = 0.f;
        #pragma unroll
        for (int qd = 0; qd < 4; ++qd) {
            float4 hv = hs[qd];
            int f = qd * 4;
            t += fmaxf(dc * (acc[tid][f + 0] + hv.x) + b1s[f + 0], 0.f) * W2s[f + 0];
            t += fmaxf(dc * (acc[tid][f + 1] + hv.y) + b1s[f + 1], 0.f) * W2s[f + 1];
            t += fmaxf(dc * (acc[tid][f + 2] + hv.z) + b1s[f + 2], 0.f) * W2s[f + 2];
            t += fmaxf(dc * (acc[tid][f + 3] + hv.w) + b1s[f + 3], 0.f) * W2s[f + 3];
        }
        q[node] = dc * t;
    }
}

// layer-2: a2[rem] += w*q[r]; out = b2 + dinv*(a2 + q_self)
__global__ __launch_bounds__(256) void k_gather2(
    const int* __restrict__ gBase, const uint2* __restrict__ edata,
    const float* __restrict__ dinv, const float* __restrict__ q,
    const float* __restrict__ b2, float* __restrict__ out, int N) {
    __shared__ float a2[BNODES];
    const int tid = threadIdx.x;
    if (tid < BNODES) a2[tid] = 0.f;
    __syncthreads();
    const int s = gBase[blockIdx.x], e = gBase[blockIdx.x + 1];
    for (int i = s + tid; i < e; i += 512) {
        uint2 ed0 = edata[i];
        int i1 = i + 256;
        uint2 ed1 = (i1 < e) ? edata[i1] : make_uint2(0u, 0u);
        float v0 = __uint_as_float(ed0.y) * q[ed0.x & 0xFFFFF];
        float v1 = __uint_as_float(ed1.y) * q[ed1.x & 0xFFFFF];
        atomicAdd(&a2[ed0.x >> 20], v0);
        atomicAdd(&a2[ed1.x >> 20], v1);
    }
    __syncthreads();
    int node = (blockIdx.x << BSH) + tid;
    if (tid < BNODES && node < N)
        out[node] = b2[0] + dinv[node] * (a2[tid] + q[node]);
}

extern "C" void kernel_launch(void* const* d_in, const int* in_sizes, int n_in,
                              void* d_out, int out_size, void* d_ws, size_t ws_size,
                              hipStream_t stream) {
    const float* x  = (const float*)d_in[0];
    const int*   ei = (const int*)d_in[1];
    const float* ew = (const float*)d_in[2];
    const float* W1 = (const float*)d_in[3];
    const float* b1 = (const float*)d_in[4];
    const float* W2 = (const float*)d_in[5];
    const float* b2 = (const float*)d_in[6];
    float* out = (float*)d_out;

    const int N = in_sizes[0] / 128;       // 100000
    const int E = in_sizes[2];             // 3200000
    const int* row = ei;
    const int* col = ei + E;
    const int NB = (N + BNODES - 1) >> BSH;  // 782

    int* gCnt    = (int*)d_ws;             // NB
    int* gBase   = gCnt + NB;              // NB+1
    int* gCursor = gBase + NB + 1;         // NB
    float* dinv  = (float*)(gCursor + NB); // N
    float* hd    = dinv + N;               // 16N  (pre-scaled h~)
    float* q     = hd + (size_t)16 * N;    // N
    uintptr_t ep = (uintptr_t)(q + N);
    ep = (ep + 7) & ~(uintptr_t)7;
    uint2* edata = (uint2*)ep;             // E

    const int ablocks = (E + CHUNK - 1) / CHUNK;   // 782

    hipMemsetAsync(gCnt, 0, (size_t)NB * sizeof(int), stream);
    k_Ahist<<<ablocks, 256, 0, stream>>>(col, gCnt, E, NB);
    k_Ascan<<<1, 1024, 0, stream>>>(gCnt, gBase, gCursor, NB, E);
    k_Ascatter<<<ablocks, 256, 0, stream>>>(row, col, ew, gCursor, edata, E, NB);
    k_deg<<<NB, 256, 0, stream>>>(gBase, edata, dinv, N);
    k_h1<<<N / 16, 256, 0, stream>>>(x, W1, dinv, hd);
    k_gather1<<<NB, 256, 0, stream>>>(gBase, edata, hd, dinv, b1, W2, q, N);
    k_gather2<<<NB, 256, 0, stream>>>(gBase, edata, dinv, q, b2, out, N);
}

// Round 6
// 523.842 us; speedup vs baseline: 1.1316x; 1.1316x over previous
//
#include <hip/hip_runtime.h>

// SectorGCN R6: 64-node bucket counting-sort (NB=1563) + sliced 16-lane-group
// gather (NSLICE=4 -> 6252 blocks, unroll x4), pre-scaled h~ = dinv*(x@W1),
// sliced deg/gather2 with LDS partials + 1 global atomic per node.
// N=100000, E=3200000, d_in=128, d_h=16.

#define DH 16
#define BSH 6
#define BNODES 64
#define NB_MAX 1568
#define CHUNK 4096        // scatter chunk
#define HCHUNK 8192       // hist chunk
#define NSLICE 4

__global__ __launch_bounds__(256) void k_Ahist(const int* __restrict__ col,
                                               int* __restrict__ gCnt, int E, int NB) {
    __shared__ int lh[NB_MAX];
    const int tid = threadIdx.x;
    for (int i = tid; i < NB; i += 256) lh[i] = 0;
    __syncthreads();
    const int base = blockIdx.x * HCHUNK;
    #pragma unroll
    for (int k = 0; k < 32; ++k) {
        int e = base + tid + 256 * k;
        if (e < E) atomicAdd(&lh[col[e] >> BSH], 1);
    }
    __syncthreads();
    for (int i = tid; i < NB; i += 256) {
        int v = lh[i];
        if (v) atomicAdd(&gCnt[i], v);
    }
}

// exclusive scan of gCnt[NB], NB <= 2048 (2 elems/thread)
__global__ __launch_bounds__(1024) void k_Ascan(const int* __restrict__ gCnt,
                                                int* __restrict__ gBase,
                                                int* __restrict__ gCursor,
                                                int NB, int E) {
    __shared__ int s[1024];
    const int t = threadIdx.x;
    const int i0 = 2 * t, i1 = 2 * t + 1;
    int a = (i0 < NB) ? gCnt[i0] : 0;
    int b = (i1 < NB) ? gCnt[i1] : 0;
    int v = a + b;
    s[t] = v;
    __syncthreads();
    for (int off = 1; off < 1024; off <<= 1) {
        int u = (t >= off) ? s[t - off] : 0;
        __syncthreads();
        s[t] += u;
        __syncthreads();
    }
    int ex = s[t] - v;
    if (i0 < NB) { gBase[i0] = ex;     gCursor[i0] = ex; }
    if (i1 < NB) { gBase[i1] = ex + a; gCursor[i1] = ex + a; }
    if (t == 0) gBase[NB] = E;
}

// LDS-staged scatter: count -> local scan -> per-(block,bucket) run
// reservation -> place sorted in LDS -> linear (coalesced-run) write-out.
__global__ __launch_bounds__(256) void k_Ascatter(const int* __restrict__ row,
                                                  const int* __restrict__ col,
                                                  const float* __restrict__ ew,
                                                  int* __restrict__ gCursor,
                                                  uint2* __restrict__ edata,
                                                  int E, int NB) {
    __shared__ int lh[NB_MAX];      // counts, then (globalRun - localBase)
    __shared__ int lbase[NB_MAX];
    __shared__ int lcur[NB_MAX];
    __shared__ int tsum[256];
    __shared__ unsigned short sbuck[CHUNK];
    __shared__ uint2 stage[CHUNK];  // 32 KB
    const int tid = threadIdx.x;
    for (int i = tid; i < NB; i += 256) lh[i] = 0;
    __syncthreads();
    const int base = blockIdx.x * CHUNK;
    int r_[16], c_[16];
    float w_[16];
    #pragma unroll
    for (int k = 0; k < 16; ++k) {
        int e = base + tid + 256 * k;
        bool ok = e < E;
        c_[k] = ok ? col[e] : -1;
        r_[k] = ok ? row[e] : 0;
        w_[k] = ok ? ew[e] : 0.f;
        if (ok) atomicAdd(&lh[c_[k] >> BSH], 1);
    }
    __syncthreads();
    // local exclusive scan, 8 buckets per thread
    const int t0 = tid * 8;
    int c8[8];
    int mysum = 0;
    #pragma unroll
    for (int k = 0; k < 8; ++k) {
        c8[k] = (t0 + k < NB) ? lh[t0 + k] : 0;
        mysum += c8[k];
    }
    tsum[tid] = mysum;
    __syncthreads();
    for (int off = 1; off < 256; off <<= 1) {
        int u = (tid >= off) ? tsum[tid - off] : 0;
        __syncthreads();
        tsum[tid] += u;
        __syncthreads();
    }
    int p = tsum[tid] - mysum;
    #pragma unroll
    for (int k = 0; k < 8; ++k) {
        if (t0 + k < NB) { lbase[t0 + k] = p; lcur[t0 + k] = p; }
        p += c8[k];
    }
    __syncthreads();
    // reserve global runs; lh[b] := globalRun - localBase
    for (int b = tid; b < NB; b += 256) {
        int cnt = lh[b];
        if (cnt) {
            int g = atomicAdd(&gCursor[b], cnt);
            lh[b] = g - lbase[b];
        }
    }
    __syncthreads();
    // place sorted into LDS
    #pragma unroll
    for (int k = 0; k < 16; ++k) {
        if (c_[k] >= 0) {
            int b = c_[k] >> BSH;
            unsigned rem = (unsigned)(c_[k] & (BNODES - 1));
            int sp = atomicAdd(&lcur[b], 1);
            stage[sp] = make_uint2((unsigned)r_[k] | (rem << 20), __float_as_uint(w_[k]));
            sbuck[sp] = (unsigned short)b;
        }
    }
    __syncthreads();
    int nE = E - base;
    if (nE > CHUNK) nE = CHUNK;
    for (int j = tid; j < nE; j += 256)
        edata[lh[sbuck[j]] + j] = stage[j];
}

// sliced degree: dg[rem] partial in LDS, one global atomic per node per slice
__global__ __launch_bounds__(256) void k_deg(const int* __restrict__ gBase,
                                             const uint2* __restrict__ edata,
                                             float* __restrict__ deg, int N) {
    __shared__ float dg[BNODES];
    const int tid = threadIdx.x;
    if (tid < BNODES) dg[tid] = 0.f;
    __syncthreads();
    const int b = blockIdx.x;
    const int s = gBase[b], e = gBase[b + 1];
    for (int i = s + blockIdx.y * 256 + tid; i < e; i += 512) {
        uint2 ed = edata[i];
        atomicAdd(&dg[ed.x >> 20], __uint_as_float(ed.y));
    }
    __syncthreads();
    int node = (b << BSH) + tid;
    if (tid < BNODES && node < N && dg[tid] != 0.f)
        atomicAdd(&deg[node], dg[tid]);
}

// h~ = rsqrt(deg+1) * (x @ W1); also stores dinv. 16 nodes x 16 feats / block.
__global__ __launch_bounds__(256) void k_h1(const float* __restrict__ x,
                                            const float* __restrict__ W1,
                                            const float* __restrict__ deg,
                                            float* __restrict__ dinv,
                                            float* __restrict__ hd) {
    __shared__ float Ws[128 * DH];
    __shared__ float xs[16 * 132];
    const int t = threadIdx.x;
    const int node0 = blockIdx.x * 16;
    #pragma unroll
    for (int i = 0; i < 8; ++i) Ws[t + 256 * i] = W1[t + 256 * i];
    const float4* xg = (const float4*)(x + (size_t)node0 * 128);
    #pragma unroll
    for (int it = 0; it < 2; ++it) {
        int idx = t + 256 * it;
        int n = idx >> 5, k4 = idx & 31;
        float4 v = xg[n * 32 + k4];
        *(float4*)(&xs[n * 132 + k4 * 4]) = v;
    }
    __syncthreads();
    const int node = t >> 4, feat = t & 15;
    const float* xr = &xs[node * 132];
    float acc = 0.f;
    #pragma unroll 8
    for (int k = 0; k < 128; ++k) acc += xr[k] * Ws[k * DH + feat];
    const int v = node0 + node;
    const float di = rsqrtf(deg[v] + 1.0f);
    if (feat == 0) dinv[v] = di;
    hd[(size_t)v * DH + feat] = di * acc;
}

// sliced layer-1 gather: block (bucket b, slice sl); 16 groups x 16 feats,
// unroll x4; acc[rem][f] += w * h~[r][f]; writes 64x16 partial strip.
__global__ __launch_bounds__(256) void k_gather1(
    const int* __restrict__ gBase, const uint2* __restrict__ edata,
    const float* __restrict__ hd, float* __restrict__ partial) {
    __shared__ float acc[BNODES][DH + 1];
    const int tid = threadIdx.x;
    for (int i = tid; i < BNODES * (DH + 1); i += 256) ((float*)acc)[i] = 0.f;
    __syncthreads();
    const int b = blockIdx.x, sl = blockIdx.y;
    const int s = gBase[b], e = gBase[b + 1];
    const int g = tid >> 4, f = tid & 15;
    for (int i = s + sl * 16 + g; i < e; i += 256) {
        uint2 e0 = edata[i];
        uint2 e1 = (i + 64  < e) ? edata[i + 64]  : make_uint2(0u, 0u);
        uint2 e2 = (i + 128 < e) ? edata[i + 128] : make_uint2(0u, 0u);
        uint2 e3 = (i + 192 < e) ? edata[i + 192] : make_uint2(0u, 0u);
        float v0 = __uint_as_float(e0.y) * hd[(size_t)(e0.x & 0xFFFFF) * DH + f];
        float v1 = __uint_as_float(e1.y) * hd[(size_t)(e1.x & 0xFFFFF) * DH + f];
        float v2 = __uint_as_float(e2.y) * hd[(size_t)(e2.x & 0xFFFFF) * DH + f];
        float v3 = __uint_as_float(e3.y) * hd[(size_t)(e3.x & 0xFFFFF) * DH + f];
        atomicAdd(&acc[e0.x >> 20][f], v0);
        atomicAdd(&acc[e1.x >> 20][f], v1);
        atomicAdd(&acc[e2.x >> 20][f], v2);
        atomicAdd(&acc[e3.x >> 20][f], v3);
    }
    __syncthreads();
    float* ps = partial + ((size_t)b * NSLICE + sl) * (DH * BNODES);
    for (int i = tid; i < DH * BNODES; i += 256)
        ps[i] = acc[i >> 4][i & 15];
}

// reduce slices + self-loop + bias + relu + dot(W2) -> q ; init out
__global__ __launch_bounds__(256) void k_fin1(
    const float* __restrict__ partial, const float* __restrict__ dinv,
    const float* __restrict__ hd, const float* __restrict__ b1,
    const float* __restrict__ W2, const float* __restrict__ b2,
    float* __restrict__ q, float* __restrict__ out, int N) {
    __shared__ float acc[BNODES][DH + 1];
    __shared__ float b1s[DH], W2s[DH];
    const int tid = threadIdx.x;
    if (tid < DH) { b1s[tid] = b1[tid]; W2s[tid] = W2[tid]; }
    const int b = blockIdx.x;
    const float* ps = partial + (size_t)b * NSLICE * (DH * BNODES);
    for (int i = tid; i < DH * BNODES; i += 256) {
        float s = 0.f;
        #pragma unroll
        for (int sl = 0; sl < NSLICE; ++sl) s += ps[sl * (DH * BNODES) + i];
        acc[i >> 4][i & 15] = s;
    }
    __syncthreads();
    int node = (b << BSH) + tid;
    if (tid < BNODES && node < N) {
        float dc = dinv[node];
        const float4* hs = (const float4*)(hd + (size_t)node * DH);
        float t = 0.f;
        #pragma unroll
        for (int qd = 0; qd < 4; ++qd) {
            float4 hv = hs[qd];
            int f = qd * 4;
            t += fmaxf(dc * (acc[tid][f + 0] + hv.x) + b1s[f + 0], 0.f) * W2s[f + 0];
            t += fmaxf(dc * (acc[tid][f + 1] + hv.y) + b1s[f + 1], 0.f) * W2s[f + 1];
            t += fmaxf(dc * (acc[tid][f + 2] + hv.z) + b1s[f + 2], 0.f) * W2s[f + 2];
            t += fmaxf(dc * (acc[tid][f + 3] + hv.w) + b1s[f + 3], 0.f) * W2s[f + 3];
        }
        float qq = dc * t;
        q[node] = qq;
        out[node] = b2[0] + dc * qq;    // bias + self-loop term of layer 2
    }
}

// sliced layer-2: a2[rem] += w*q[r]; out[node] += dinv*a2 (1 atomic/node/slice)
__global__ __launch_bounds__(256) void k_gather2(
    const int* __restrict__ gBase, const uint2* __restrict__ edata,
    const float* __restrict__ dinv, const float* __restrict__ q,
    float* __restrict__ out, int N) {
    __shared__ float a2[BNODES];
    const int tid = threadIdx.x;
    if (tid < BNODES) a2[tid] = 0.f;
    __syncthreads();
    const int b = blockIdx.x;
    const int s = gBase[b], e = gBase[b + 1];
    for (int i = s + blockIdx.y * 256 + tid; i < e; i += 512) {
        uint2 ed = edata[i];
        atomicAdd(&a2[ed.x >> 20], __uint_as_float(ed.y) * q[ed.x & 0xFFFFF]);
    }
    __syncthreads();
    int node = (b << BSH) + tid;
    if (tid < BNODES && node < N && a2[tid] != 0.f)
        atomicAdd(&out[node], dinv[node] * a2[tid]);
}

extern "C" void kernel_launch(void* const* d_in, const int* in_sizes, int n_in,
                              void* d_out, int out_size, void* d_ws, size_t ws_size,
                              hipStream_t stream) {
    const float* x  = (const float*)d_in[0];
    const int*   ei = (const int*)d_in[1];
    const float* ew = (const float*)d_in[2];
    const float* W1 = (const float*)d_in[3];
    const float* b1 = (const float*)d_in[4];
    const float* W2 = (const float*)d_in[5];
    const float* b2 = (const float*)d_in[6];
    float* out = (float*)d_out;

    const int N = in_sizes[0] / 128;       // 100000
    const int E = in_sizes[2];             // 3200000
    const int* row = ei;
    const int* col = ei + E;
    const int NB = (N + BNODES - 1) >> BSH;   // 1563
    const int NBp = (NB + 3) & ~3;            // padded for 16B alignment

    int* gCnt    = (int*)d_ws;                 // NBp
    float* deg   = (float*)(gCnt + NBp);       // N   (memset together with gCnt)
    int* gBase   = (int*)(deg + N);            // NBp (uses NB+1)
    int* gCursor = gBase + NBp;                // NBp
    float* dinv  = (float*)(gCursor + NBp);    // N
    float* hd    = dinv + N;                   // 16N  (16B-aligned)
    float* q     = hd + (size_t)16 * N;        // N
    float* partial = q + N;                    // NB*NSLICE*1024 floats = 25.6 MB
    uintptr_t ep = (uintptr_t)(partial + (size_t)NB * NSLICE * (DH * BNODES));
    ep = (ep + 15) & ~(uintptr_t)15;
    uint2* edata = (uint2*)ep;                 // E

    const int hblocks = (E + HCHUNK - 1) / HCHUNK;  // 391
    const int sblocks = (E + CHUNK - 1) / CHUNK;    // 782

    hipMemsetAsync(gCnt, 0, ((size_t)NBp + N) * sizeof(int), stream);
    k_Ahist<<<hblocks, 256, 0, stream>>>(col, gCnt, E, NB);
    k_Ascan<<<1, 1024, 0, stream>>>(gCnt, gBase, gCursor, NB, E);
    k_Ascatter<<<sblocks, 256, 0, stream>>>(row, col, ew, gCursor, edata, E, NB);
    k_deg<<<dim3(NB, 2), 256, 0, stream>>>(gBase, edata, deg, N);
    k_h1<<<N / 16, 256, 0, stream>>>(x, W1, deg, dinv, hd);
    k_gather1<<<dim3(NB, NSLICE), 256, 0, stream>>>(gBase, edata, hd, partial);
    k_fin1<<<NB, 256, 0, stream>>>(partial, dinv, hd, b1, W2, b2, q, out, N);
    k_gather2<<<dim3(NB, 2), 256, 0, stream>>>(gBase, edata, dinv, q, out, N);
}

// Round 7
// 522.859 us; speedup vs baseline: 1.1337x; 1.0019x over previous
//
#include <hip/hip_runtime.h>
#include <hip/hip_bf16.h>

// SectorGCN R7: R6 structure + bf16 h~ (3.2 MB < 4 MB per-XCD L2 -> random
// gather becomes L2-resident) and bf16 q for layer-2 random reads.
// 64-node buckets (NB=1563), sliced gathers, LDS-staged coalesced scatter.
// N=100000, E=3200000, d_in=128, d_h=16.

#define DH 16
#define BSH 6
#define BNODES 64
#define NB_MAX 1568
#define CHUNK 4096        // scatter chunk
#define HCHUNK 8192       // hist chunk
#define NSLICE 4

__global__ __launch_bounds__(256) void k_Ahist(const int* __restrict__ col,
                                               int* __restrict__ gCnt, int E, int NB) {
    __shared__ int lh[NB_MAX];
    const int tid = threadIdx.x;
    for (int i = tid; i < NB; i += 256) lh[i] = 0;
    __syncthreads();
    const int base = blockIdx.x * HCHUNK;
    #pragma unroll
    for (int k = 0; k < 32; ++k) {
        int e = base + tid + 256 * k;
        if (e < E) atomicAdd(&lh[col[e] >> BSH], 1);
    }
    __syncthreads();
    for (int i = tid; i < NB; i += 256) {
        int v = lh[i];
        if (v) atomicAdd(&gCnt[i], v);
    }
}

// exclusive scan of gCnt[NB], NB <= 2048 (2 elems/thread)
__global__ __launch_bounds__(1024) void k_Ascan(const int* __restrict__ gCnt,
                                                int* __restrict__ gBase,
                                                int* __restrict__ gCursor,
                                                int NB, int E) {
    __shared__ int s[1024];
    const int t = threadIdx.x;
    const int i0 = 2 * t, i1 = 2 * t + 1;
    int a = (i0 < NB) ? gCnt[i0] : 0;
    int b = (i1 < NB) ? gCnt[i1] : 0;
    int v = a + b;
    s[t] = v;
    __syncthreads();
    for (int off = 1; off < 1024; off <<= 1) {
        int u = (t >= off) ? s[t - off] : 0;
        __syncthreads();
        s[t] += u;
        __syncthreads();
    }
    int ex = s[t] - v;
    if (i0 < NB) { gBase[i0] = ex;     gCursor[i0] = ex; }
    if (i1 < NB) { gBase[i1] = ex + a; gCursor[i1] = ex + a; }
    if (t == 0) gBase[NB] = E;
}

// LDS-staged scatter: count -> local scan -> per-(block,bucket) run
// reservation -> place sorted in LDS -> linear (coalesced-run) write-out.
__global__ __launch_bounds__(256) void k_Ascatter(const int* __restrict__ row,
                                                  const int* __restrict__ col,
                                                  const float* __restrict__ ew,
                                                  int* __restrict__ gCursor,
                                                  uint2* __restrict__ edata,
                                                  int E, int NB) {
    __shared__ int lh[NB_MAX];      // counts, then (globalRun - localBase)
    __shared__ int lbase[NB_MAX];
    __shared__ int lcur[NB_MAX];
    __shared__ int tsum[256];
    __shared__ unsigned short sbuck[CHUNK];
    __shared__ uint2 stage[CHUNK];  // 32 KB
    const int tid = threadIdx.x;
    for (int i = tid; i < NB; i += 256) lh[i] = 0;
    __syncthreads();
    const int base = blockIdx.x * CHUNK;
    int r_[16], c_[16];
    float w_[16];
    #pragma unroll
    for (int k = 0; k < 16; ++k) {
        int e = base + tid + 256 * k;
        bool ok = e < E;
        c_[k] = ok ? col[e] : -1;
        r_[k] = ok ? row[e] : 0;
        w_[k] = ok ? ew[e] : 0.f;
        if (ok) atomicAdd(&lh[c_[k] >> BSH], 1);
    }
    __syncthreads();
    const int t0 = tid * 8;
    int c8[8];
    int mysum = 0;
    #pragma unroll
    for (int k = 0; k < 8; ++k) {
        c8[k] = (t0 + k < NB) ? lh[t0 + k] : 0;
        mysum += c8[k];
    }
    tsum[tid] = mysum;
    __syncthreads();
    for (int off = 1; off < 256; off <<= 1) {
        int u = (tid >= off) ? tsum[tid - off] : 0;
        __syncthreads();
        tsum[tid] += u;
        __syncthreads();
    }
    int p = tsum[tid] - mysum;
    #pragma unroll
    for (int k = 0; k < 8; ++k) {
        if (t0 + k < NB) { lbase[t0 + k] = p; lcur[t0 + k] = p; }
        p += c8[k];
    }
    __syncthreads();
    for (int b = tid; b < NB; b += 256) {
        int cnt = lh[b];
        if (cnt) {
            int g = atomicAdd(&gCursor[b], cnt);
            lh[b] = g - lbase[b];
        }
    }
    __syncthreads();
    #pragma unroll
    for (int k = 0; k < 16; ++k) {
        if (c_[k] >= 0) {
            int b = c_[k] >> BSH;
            unsigned rem = (unsigned)(c_[k] & (BNODES - 1));
            int sp = atomicAdd(&lcur[b], 1);
            stage[sp] = make_uint2((unsigned)r_[k] | (rem << 20), __float_as_uint(w_[k]));
            sbuck[sp] = (unsigned short)b;
        }
    }
    __syncthreads();
    int nE = E - base;
    if (nE > CHUNK) nE = CHUNK;
    for (int j = tid; j < nE; j += 256)
        edata[lh[sbuck[j]] + j] = stage[j];
}

// sliced degree: dg[rem] partial in LDS, one global atomic per node per slice
__global__ __launch_bounds__(256) void k_deg(const int* __restrict__ gBase,
                                             const uint2* __restrict__ edata,
                                             float* __restrict__ deg, int N) {
    __shared__ float dg[BNODES];
    const int tid = threadIdx.x;
    if (tid < BNODES) dg[tid] = 0.f;
    __syncthreads();
    const int b = blockIdx.x;
    const int s = gBase[b], e = gBase[b + 1];
    for (int i = s + blockIdx.y * 256 + tid; i < e; i += 512) {
        uint2 ed = edata[i];
        atomicAdd(&dg[ed.x >> 20], __uint_as_float(ed.y));
    }
    __syncthreads();
    int node = (b << BSH) + tid;
    if (tid < BNODES && node < N && dg[tid] != 0.f)
        atomicAdd(&deg[node], dg[tid]);
}

// h~ = rsqrt(deg+1) * (x @ W1) stored as bf16; also stores dinv (fp32).
__global__ __launch_bounds__(256) void k_h1(const float* __restrict__ x,
                                            const float* __restrict__ W1,
                                            const float* __restrict__ deg,
                                            float* __restrict__ dinv,
                                            __hip_bfloat16* __restrict__ hdb) {
    __shared__ float Ws[128 * DH];
    __shared__ float xs[16 * 132];
    const int t = threadIdx.x;
    const int node0 = blockIdx.x * 16;
    #pragma unroll
    for (int i = 0; i < 8; ++i) Ws[t + 256 * i] = W1[t + 256 * i];
    const float4* xg = (const float4*)(x + (size_t)node0 * 128);
    #pragma unroll
    for (int it = 0; it < 2; ++it) {
        int idx = t + 256 * it;
        int n = idx >> 5, k4 = idx & 31;
        float4 v = xg[n * 32 + k4];
        *(float4*)(&xs[n * 132 + k4 * 4]) = v;
    }
    __syncthreads();
    const int node = t >> 4, feat = t & 15;
    const float* xr = &xs[node * 132];
    float acc = 0.f;
    #pragma unroll 8
    for (int k = 0; k < 128; ++k) acc += xr[k] * Ws[k * DH + feat];
    const int v = node0 + node;
    const float di = rsqrtf(deg[v] + 1.0f);
    if (feat == 0) dinv[v] = di;
    hdb[(size_t)v * DH + feat] = __float2bfloat16(di * acc);
}

// sliced layer-1 gather: 16 groups x 16 feats, unroll x4;
// acc[rem][f] += w * h~[r][f] (h~ bf16, L2-resident); 64x16 partial strip out.
__global__ __launch_bounds__(256) void k_gather1(
    const int* __restrict__ gBase, const uint2* __restrict__ edata,
    const __hip_bfloat16* __restrict__ hdb, float* __restrict__ partial) {
    __shared__ float acc[BNODES][DH + 1];
    const int tid = threadIdx.x;
    for (int i = tid; i < BNODES * (DH + 1); i += 256) ((float*)acc)[i] = 0.f;
    __syncthreads();
    const int b = blockIdx.x, sl = blockIdx.y;
    const int s = gBase[b], e = gBase[b + 1];
    const int g = tid >> 4, f = tid & 15;
    for (int i = s + sl * 16 + g; i < e; i += 256) {
        uint2 e0 = edata[i];
        uint2 e1 = (i + 64  < e) ? edata[i + 64]  : make_uint2(0u, 0u);
        uint2 e2 = (i + 128 < e) ? edata[i + 128] : make_uint2(0u, 0u);
        uint2 e3 = (i + 192 < e) ? edata[i + 192] : make_uint2(0u, 0u);
        float h0 = __bfloat162float(hdb[(size_t)(e0.x & 0xFFFFF) * DH + f]);
        float h1 = __bfloat162float(hdb[(size_t)(e1.x & 0xFFFFF) * DH + f]);
        float h2 = __bfloat162float(hdb[(size_t)(e2.x & 0xFFFFF) * DH + f]);
        float h3 = __bfloat162float(hdb[(size_t)(e3.x & 0xFFFFF) * DH + f]);
        atomicAdd(&acc[e0.x >> 20][f], __uint_as_float(e0.y) * h0);
        atomicAdd(&acc[e1.x >> 20][f], __uint_as_float(e1.y) * h1);
        atomicAdd(&acc[e2.x >> 20][f], __uint_as_float(e2.y) * h2);
        atomicAdd(&acc[e3.x >> 20][f], __uint_as_float(e3.y) * h3);
    }
    __syncthreads();
    float* ps = partial + ((size_t)b * NSLICE + sl) * (DH * BNODES);
    for (int i = tid; i < DH * BNODES; i += 256)
        ps[i] = acc[i >> 4][i & 15];
}

// reduce slices + self-loop + bias + relu + dot(W2) -> q (bf16) ; init out
__global__ __launch_bounds__(256) void k_fin1(
    const float* __restrict__ partial, const float* __restrict__ dinv,
    const __hip_bfloat16* __restrict__ hdb, const float* __restrict__ b1,
    const float* __restrict__ W2, const float* __restrict__ b2,
    __hip_bfloat16* __restrict__ qb, float* __restrict__ out, int N) {
    __shared__ float acc[BNODES][DH + 1];
    __shared__ float b1s[DH], W2s[DH];
    const int tid = threadIdx.x;
    if (tid < DH) { b1s[tid] = b1[tid]; W2s[tid] = W2[tid]; }
    const int b = blockIdx.x;
    const float* ps = partial + (size_t)b * NSLICE * (DH * BNODES);
    for (int i = tid; i < DH * BNODES; i += 256) {
        float s = 0.f;
        #pragma unroll
        for (int sl = 0; sl < NSLICE; ++sl) s += ps[sl * (DH * BNODES) + i];
        acc[i >> 4][i & 15] = s;
    }
    __syncthreads();
    int node = (b << BSH) + tid;
    if (tid < BNODES && node < N) {
        float dc = dinv[node];
        const __hip_bfloat16* hs = hdb + (size_t)node * DH;
        float t = 0.f;
        #pragma unroll
        for (int f = 0; f < DH; ++f) {
            float hv = __bfloat162float(hs[f]);
            t += fmaxf(dc * (acc[tid][f] + hv) + b1s[f], 0.f) * W2s[f];
        }
        float qq = dc * t;
        qb[node] = __float2bfloat16(qq);
        out[node] = b2[0] + dc * qq;    // bias + self-loop term of layer 2
    }
}

// sliced layer-2: a2[rem] += w*q[r] (q bf16, L2-resident);
// out[node] += dinv*a2 (1 global atomic per node per slice)
__global__ __launch_bounds__(256) void k_gather2(
    const int* __restrict__ gBase, const uint2* __restrict__ edata,
    const float* __restrict__ dinv, const __hip_bfloat16* __restrict__ qb,
    float* __restrict__ out, int N) {
    __shared__ float a2[BNODES];
    const int tid = threadIdx.x;
    if (tid < BNODES) a2[tid] = 0.f;
    __syncthreads();
    const int b = blockIdx.x;
    const int s = gBase[b], e = gBase[b + 1];
    for (int i = s + blockIdx.y * 256 + tid; i < e; i += 512) {
        uint2 ed = edata[i];
        float qv = __bfloat162float(qb[ed.x & 0xFFFFF]);
        atomicAdd(&a2[ed.x >> 20], __uint_as_float(ed.y) * qv);
    }
    __syncthreads();
    int node = (b << BSH) + tid;
    if (tid < BNODES && node < N && a2[tid] != 0.f)
        atomicAdd(&out[node], dinv[node] * a2[tid]);
}

extern "C" void kernel_launch(void* const* d_in, const int* in_sizes, int n_in,
                              void* d_out, int out_size, void* d_ws, size_t ws_size,
                              hipStream_t stream) {
    const float* x  = (const float*)d_in[0];
    const int*   ei = (const int*)d_in[1];
    const float* ew = (const float*)d_in[2];
    const float* W1 = (const float*)d_in[3];
    const float* b1 = (const float*)d_in[4];
    const float* W2 = (const float*)d_in[5];
    const float* b2 = (const float*)d_in[6];
    float* out = (float*)d_out;

    const int N = in_sizes[0] / 128;       // 100000
    const int E = in_sizes[2];             // 3200000
    const int* row = ei;
    const int* col = ei + E;
    const int NB = (N + BNODES - 1) >> BSH;   // 1563
    const int NBp = (NB + 3) & ~3;

    int* gCnt    = (int*)d_ws;                 // NBp
    float* deg   = (float*)(gCnt + NBp);       // N (memset with gCnt)
    int* gBase   = (int*)(deg + N);            // NBp (uses NB+1)
    int* gCursor = gBase + NBp;                // NBp
    float* dinv  = (float*)(gCursor + NBp);    // N
    __hip_bfloat16* hdb = (__hip_bfloat16*)(dinv + N);   // 16N bf16 = 3.2 MB
    __hip_bfloat16* qb  = hdb + (size_t)16 * N;          // N bf16
    uintptr_t pp = (uintptr_t)(qb + N);
    pp = (pp + 15) & ~(uintptr_t)15;
    float* partial = (float*)pp;               // NB*NSLICE*1024 floats = 25.6 MB
    uintptr_t ep = (uintptr_t)(partial + (size_t)NB * NSLICE * (DH * BNODES));
    ep = (ep + 15) & ~(uintptr_t)15;
    uint2* edata = (uint2*)ep;                 // E

    const int hblocks = (E + HCHUNK - 1) / HCHUNK;  // 391
    const int sblocks = (E + CHUNK - 1) / CHUNK;    // 782

    hipMemsetAsync(gCnt, 0, ((size_t)NBp + N) * sizeof(int), stream);
    k_Ahist<<<hblocks, 256, 0, stream>>>(col, gCnt, E, NB);
    k_Ascan<<<1, 1024, 0, stream>>>(gCnt, gBase, gCursor, NB, E);
    k_Ascatter<<<sblocks, 256, 0, stream>>>(row, col, ew, gCursor, edata, E, NB);
    k_deg<<<dim3(NB, 2), 256, 0, stream>>>(gBase, edata, deg, N);
    k_h1<<<N / 16, 256, 0, stream>>>(x, W1, deg, dinv, hdb);
    k_gather1<<<dim3(NB, NSLICE), 256, 0, stream>>>(gBase, edata, hdb, partial);
    k_fin1<<<NB, 256, 0, stream>>>(partial, dinv, hdb, b1, W2, b2, qb, out, N);
    k_gather2<<<dim3(NB, 2), 256, 0, stream>>>(gBase, edata, dinv, qb, out, N);
}